// Round 4
// baseline (4304.534 us; speedup 1.0000x reference)
//
#include <hip/hip_runtime.h>
#include <math.h>

#define HID 128
#define EPS 1e-5f
#define BK 64          // dst nodes per bucket
#define MAXNBK 2048    // supports n <= 131072

// ---------------- bucketed graph preprocessing ----------------
// btmp entry: (src << 6) | (dst & 63)  -- src < 2^26 required (n=1e5 ok)

// per-block LDS histogram of dst buckets -> global bcount (padded *16 = one line each)
__global__ __launch_bounds__(256) void k_bhist(const int* __restrict__ dst, int* __restrict__ bcount,
                                               int e, int nbk) {
    __shared__ int hist[MAXNBK];
    for (int i = threadIdx.x; i < nbk; i += 256) hist[i] = 0;
    __syncthreads();
    int base = blockIdx.x * 4096;
    int end = min(base + 4096, e);
    for (int i = base + threadIdx.x; i < end; i += 256) atomicAdd(&hist[dst[i] >> 6], 1);
    __syncthreads();
    for (int i = threadIdx.x; i < nbk; i += 256) {
        int c = hist[i];
        if (c) atomicAdd(&bcount[i * 16], c);
    }
}

// single-block exclusive scan of bcount -> boffs[nbk+1], init bcur = boffs (padded)
__global__ __launch_bounds__(1024) void k_bscan(const int* __restrict__ bcount, int* __restrict__ boffs,
                                                int* __restrict__ bcur, int nbk, int e) {
    __shared__ int lds[1024];
    int tid = threadIdx.x;
    int i0 = 2 * tid, i1 = 2 * tid + 1;
    int a = (i0 < nbk) ? bcount[i0 * 16] : 0;
    int b = (i1 < nbk) ? bcount[i1 * 16] : 0;
    lds[tid] = a + b;
    __syncthreads();
    for (int off = 1; off < 1024; off <<= 1) {
        int v = (tid >= off) ? lds[tid - off] : 0;
        __syncthreads();
        lds[tid] += v;
        __syncthreads();
    }
    int excl = lds[tid] - (a + b);
    if (i0 < nbk) { boffs[i0] = excl;     bcur[i0 * 16] = excl; }
    if (i1 < nbk) { boffs[i1] = excl + a; bcur[i1 * 16] = excl + a; }
    if (tid == 1023) boffs[nbk] = e;
}

// scatter edges into bucket-grouped btmp; per-(block,bucket) contiguous runs
__global__ __launch_bounds__(1024) void k_bscatter(const int* __restrict__ src, const int* __restrict__ dst,
                                                   int* __restrict__ bcur, int* __restrict__ btmp,
                                                   int e, int nbk) {
    __shared__ int hist[MAXNBK];
    int tid = threadIdx.x;
    for (int i = tid; i < nbk; i += 1024) hist[i] = 0;
    __syncthreads();
    int per = (e + gridDim.x - 1) / gridDim.x;
    int base = blockIdx.x * per;
    int end = min(base + per, e);
    for (int i = base + tid; i < end; i += 1024) atomicAdd(&hist[dst[i] >> 6], 1);
    __syncthreads();
    for (int i = tid; i < nbk; i += 1024) {
        int c = hist[i];
        hist[i] = c ? atomicAdd(&bcur[i * 16], c) : 0;  // hist := global base of this block's run
    }
    __syncthreads();
    for (int i = base + tid; i < end; i += 1024) {
        int d = dst[i];
        int pos = atomicAdd(&hist[d >> 6], 1);          // LDS atomic -> global slot
        btmp[pos] = (src[i] << 6) | (d & 63);
    }
}

// per-bucket degree count -> dinv (replaces global count_deg)
__global__ __launch_bounds__(256) void k_bdinv(const int* __restrict__ btmp, const int* __restrict__ boffs,
                                               float* __restrict__ dinv, int n) {
    __shared__ int cnt[BK];
    int b = blockIdx.x, tid = threadIdx.x;
    if (tid < BK) cnt[tid] = 0;
    __syncthreads();
    int e0 = boffs[b], e1 = boffs[b + 1];
    for (int i = e0 + tid; i < e1; i += 256) atomicAdd(&cnt[btmp[i] & 63], 1);
    __syncthreads();
    if (tid < BK) {
        int node = b * BK + tid;
        if (node < n) dinv[node] = rsqrtf((float)(cnt[tid] + 1));  // +1 self-loop
    }
}

// ---------------- embed: h = relu(x @ We + be), x is [N,2] ----------------

__global__ void k_embed(const float* __restrict__ x, const float* __restrict__ We,
                        const float* __restrict__ be, float* __restrict__ h, int n) {
    int i = blockIdx.x * 256 + threadIdx.x;
    if (i >= n * HID) return;
    int node = i >> 7, j = i & 127;
    float v = x[2 * node] * We[j] + x[2 * node + 1] * We[HID + j] + be[j];
    h[i] = fmaxf(v, 0.f);
}

// ---------------- GEMM: t'[n][j] = dinv[n] * sum_k h[n][k] * W[k][j], 128x128 ---------

__global__ __launch_bounds__(256) void k_gemm128(const float* __restrict__ h, const float* __restrict__ W,
                                                 const float* __restrict__ dinv,
                                                 float* __restrict__ out, int n) {
    __shared__ float hs[128][66];
    __shared__ float ws[128][64];
    int tid = threadIdx.x;
    int nb = blockIdx.x * 64;
    const float4* h4 = (const float4*)h;
#pragma unroll
    for (int r = 0; r < 8; ++r) {
        int idx = r * 256 + tid;
        int ni = idx >> 5;
        int k4 = idx & 31;
        int node = nb + ni;
        float4 v = make_float4(0.f, 0.f, 0.f, 0.f);
        if (node < n) v = h4[(size_t)node * 32 + k4];
        hs[k4 * 4 + 0][ni] = v.x; hs[k4 * 4 + 1][ni] = v.y;
        hs[k4 * 4 + 2][ni] = v.z; hs[k4 * 4 + 3][ni] = v.w;
    }
    int fg = tid & 15, ng = tid >> 4;
    const float4* w4 = (const float4*)W;
    for (int c = 0; c < 2; ++c) {
        if (c) __syncthreads();
#pragma unroll
        for (int r = 0; r < 8; ++r) {
            int idx = r * 256 + tid;
            int k = idx >> 4, f4 = idx & 15;
            *((float4*)&ws[k][f4 * 4]) = w4[k * 32 + c * 16 + f4];
        }
        __syncthreads();
        float acc[4][4] = {{0.f}};
#pragma unroll 8
        for (int k = 0; k < 128; ++k) {
            float2 a0 = *((const float2*)&hs[k][ng * 4]);
            float2 a1 = *((const float2*)&hs[k][ng * 4 + 2]);
            float4 w = *((const float4*)&ws[k][fg * 4]);
            float av[4] = {a0.x, a0.y, a1.x, a1.y};
            float wv[4] = {w.x, w.y, w.z, w.w};
#pragma unroll
            for (int i = 0; i < 4; ++i)
#pragma unroll
                for (int j = 0; j < 4; ++j)
                    acc[i][j] += av[i] * wv[j];
        }
#pragma unroll
        for (int i = 0; i < 4; ++i) {
            int node = nb + ng * 4 + i;
            if (node < n) {
                float dv = dinv[node];
                *((float4*)&out[(size_t)node * 128 + c * 64 + fg * 4]) =
                    make_float4(acc[i][0] * dv, acc[i][1] * dv, acc[i][2] * dv, acc[i][3] * dv);
            }
        }
    }
}

// ---------------- fused bucket aggregation --------------------------------------------
// out[i] = dinv[i]*(t'[i] + sum_{s in N(i)} t'[s]) + b,  t' pre-scaled by dinv[src].
// One block per 64-node dst bucket; 32KB LDS accumulator; LDS float atomics.
// Lane l handles features l and l+64 (bank-friendly: 2-way aliasing = free).

__global__ __launch_bounds__(256) void k_agg2(const float* __restrict__ t, const int* __restrict__ btmp,
                                              const int* __restrict__ boffs, const float* __restrict__ dinv,
                                              const float* __restrict__ bias, float* __restrict__ out, int n) {
    __shared__ float acc[BK * 128];
    int tid = threadIdx.x;
    for (int i = tid; i < BK * 128; i += 256) acc[i] = 0.f;
    __syncthreads();
    int b = blockIdx.x;
    int node0 = b * BK;
    int e0 = boffs[b], e1 = boffs[b + 1];
    int lane = tid & 63, w = tid >> 6;
    int i = e0 + w * 8;
    for (; i + 8 <= e1; i += 32) {
        int p0 = btmp[i + 0], p1 = btmp[i + 1], p2 = btmp[i + 2], p3 = btmp[i + 3];
        int p4 = btmp[i + 4], p5 = btmp[i + 5], p6 = btmp[i + 6], p7 = btmp[i + 7];
        float a0 = t[(size_t)(p0 >> 6) * 128 + lane],      a1 = t[(size_t)(p1 >> 6) * 128 + lane];
        float a2 = t[(size_t)(p2 >> 6) * 128 + lane],      a3 = t[(size_t)(p3 >> 6) * 128 + lane];
        float a4 = t[(size_t)(p4 >> 6) * 128 + lane],      a5 = t[(size_t)(p5 >> 6) * 128 + lane];
        float a6 = t[(size_t)(p6 >> 6) * 128 + lane],      a7 = t[(size_t)(p7 >> 6) * 128 + lane];
        float c0 = t[(size_t)(p0 >> 6) * 128 + 64 + lane], c1 = t[(size_t)(p1 >> 6) * 128 + 64 + lane];
        float c2 = t[(size_t)(p2 >> 6) * 128 + 64 + lane], c3 = t[(size_t)(p3 >> 6) * 128 + 64 + lane];
        float c4 = t[(size_t)(p4 >> 6) * 128 + 64 + lane], c5 = t[(size_t)(p5 >> 6) * 128 + 64 + lane];
        float c6 = t[(size_t)(p6 >> 6) * 128 + 64 + lane], c7 = t[(size_t)(p7 >> 6) * 128 + 64 + lane];
        atomicAdd(&acc[(p0 & 63) * 128 + lane], a0);      atomicAdd(&acc[(p0 & 63) * 128 + 64 + lane], c0);
        atomicAdd(&acc[(p1 & 63) * 128 + lane], a1);      atomicAdd(&acc[(p1 & 63) * 128 + 64 + lane], c1);
        atomicAdd(&acc[(p2 & 63) * 128 + lane], a2);      atomicAdd(&acc[(p2 & 63) * 128 + 64 + lane], c2);
        atomicAdd(&acc[(p3 & 63) * 128 + lane], a3);      atomicAdd(&acc[(p3 & 63) * 128 + 64 + lane], c3);
        atomicAdd(&acc[(p4 & 63) * 128 + lane], a4);      atomicAdd(&acc[(p4 & 63) * 128 + 64 + lane], c4);
        atomicAdd(&acc[(p5 & 63) * 128 + lane], a5);      atomicAdd(&acc[(p5 & 63) * 128 + 64 + lane], c5);
        atomicAdd(&acc[(p6 & 63) * 128 + lane], a6);      atomicAdd(&acc[(p6 & 63) * 128 + 64 + lane], c6);
        atomicAdd(&acc[(p7 & 63) * 128 + lane], a7);      atomicAdd(&acc[(p7 & 63) * 128 + 64 + lane], c7);
    }
    for (; i < e1; ++i) {
        int p = btmp[i];
        float a = t[(size_t)(p >> 6) * 128 + lane];
        float c = t[(size_t)(p >> 6) * 128 + 64 + lane];
        atomicAdd(&acc[(p & 63) * 128 + lane], a);
        atomicAdd(&acc[(p & 63) * 128 + 64 + lane], c);
    }
    __syncthreads();
    // epilogue: add self-loop row, scale by dinv[dst], add bias; coalesced write
    for (int idx = tid; idx < BK * 128; idx += 256) {
        int nd = idx >> 7, ft = idx & 127;
        int node = node0 + nd;
        if (node < n) {
            float v = (acc[idx] + t[(size_t)node * 128 + ft]) * dinv[node] + bias[ft];
            out[(size_t)node * 128 + ft] = v;
        }
    }
}

// ---------------- BN ----------------

__global__ void k_bn_stats128(const float* __restrict__ v, float* __restrict__ S,
                              float* __restrict__ SS, int n) {
    int j = threadIdx.x;  // 128 threads
    int per = (n + gridDim.x - 1) / gridDim.x;
    int start = blockIdx.x * per;
    int end = min(start + per, n);
    float s = 0.f, ss = 0.f;
    for (int i = start; i < end; ++i) {
        float x = v[(size_t)i * 128 + j];
        s += x; ss += x * x;
    }
    atomicAdd(&S[j], s);
    atomicAdd(&SS[j], ss);
}

__global__ void k_bn_stats32(const float* __restrict__ v, float* __restrict__ S,
                             float* __restrict__ SS, int n) {
    int j = threadIdx.x & 31, sub = threadIdx.x >> 5;
    int per = (n + gridDim.x - 1) / gridDim.x;
    int start = blockIdx.x * per;
    int end = min(start + per, n);
    float s = 0.f, ss = 0.f;
    for (int i = start + sub; i < end; i += 4) {
        float x = v[(size_t)i * 32 + j];
        s += x; ss += x * x;
    }
    atomicAdd(&S[j], s);
    atomicAdd(&SS[j], ss);
}

__global__ void k_bn_finalize(const float* __restrict__ S, const float* __restrict__ SS,
                              const float* __restrict__ g, const float* __restrict__ bt,
                              float* __restrict__ A, float* __restrict__ C, int n, int hid) {
    int j = threadIdx.x;
    if (j >= hid) return;
    float mu = S[j] / (float)n;
    float var = SS[j] / (float)n - mu * mu;
    float inv = rsqrtf(var + EPS);
    A[j] = g[j] * inv;
    C[j] = bt[j] - mu * g[j] * inv;
}

// h[i] = relu(agg[i]*A + C) + h[i]
__global__ void k_bn_apply_res(const float* __restrict__ agg, const float* __restrict__ A,
                               const float* __restrict__ C, float* __restrict__ h, int total) {
    int i = blockIdx.x * 256 + threadIdx.x;
    if (i < total) {
        int j = i & 127;
        float v = agg[i] * A[j] + C[j];
        h[i] += fmaxf(v, 0.f);
    }
}

// ---------------- head GEMM: tf = h @ Wf1 + bf1 (128 -> 32) ----------------

__global__ __launch_bounds__(256) void k_gemmf(const float* __restrict__ h, const float* __restrict__ W,
                                               const float* __restrict__ bias, float* __restrict__ out, int n) {
    __shared__ float hs[128][66];
    __shared__ float ws[128][32];
    int tid = threadIdx.x;
    int nb = blockIdx.x * 64;
    const float4* h4 = (const float4*)h;
#pragma unroll
    for (int r = 0; r < 8; ++r) {
        int idx = r * 256 + tid;
        int ni = idx >> 5, k4 = idx & 31;
        int node = nb + ni;
        float4 v = make_float4(0.f, 0.f, 0.f, 0.f);
        if (node < n) v = h4[(size_t)node * 32 + k4];
        hs[k4 * 4 + 0][ni] = v.x; hs[k4 * 4 + 1][ni] = v.y;
        hs[k4 * 4 + 2][ni] = v.z; hs[k4 * 4 + 3][ni] = v.w;
    }
    const float4* w4 = (const float4*)W;
#pragma unroll
    for (int r = 0; r < 4; ++r) {
        int idx = r * 256 + tid;
        int k = idx >> 3, f4 = idx & 7;
        *((float4*)&ws[k][f4 * 4]) = w4[k * 8 + f4];
    }
    __syncthreads();
    int fg = tid & 7, ng = tid >> 3;
    float acc[2][4] = {{0.f}};
#pragma unroll 8
    for (int k = 0; k < 128; ++k) {
        float2 a = *((const float2*)&hs[k][ng * 2]);
        float4 w = *((const float4*)&ws[k][fg * 4]);
        acc[0][0] += a.x * w.x; acc[0][1] += a.x * w.y; acc[0][2] += a.x * w.z; acc[0][3] += a.x * w.w;
        acc[1][0] += a.y * w.x; acc[1][1] += a.y * w.y; acc[1][2] += a.y * w.z; acc[1][3] += a.y * w.w;
    }
    float4 bb = *((const float4*)&bias[fg * 4]);
#pragma unroll
    for (int i = 0; i < 2; ++i) {
        int node = nb + ng * 2 + i;
        if (node < n)
            *((float4*)&out[(size_t)node * 32 + fg * 4]) =
                make_float4(acc[i][0] + bb.x, acc[i][1] + bb.y, acc[i][2] + bb.z, acc[i][3] + bb.w);
    }
}

// ---------------- final: out = tanh(relu(bn(tf)) @ Wf2 + bf2) ----------------

__global__ void k_final(const float* __restrict__ tf, const float* __restrict__ A,
                        const float* __restrict__ C, const float* __restrict__ Wf2,
                        const float* __restrict__ bf2, float* __restrict__ out, int n) {
    int node = blockIdx.x * 256 + threadIdx.x;
    if (node >= n) return;
    float o0 = bf2[0], o1 = bf2[1];
    const float4* t4 = (const float4*)(tf + (size_t)node * 32);
#pragma unroll
    for (int q = 0; q < 8; ++q) {
        float4 v = t4[q];
        float vv[4] = {v.x, v.y, v.z, v.w};
#pragma unroll
        for (int r = 0; r < 4; ++r) {
            int j = q * 4 + r;
            float f = fmaxf(vv[r] * A[j] + C[j], 0.f);
            o0 += f * Wf2[2 * j];
            o1 += f * Wf2[2 * j + 1];
        }
    }
    out[2 * node] = tanhf(o0);
    out[2 * node + 1] = tanhf(o1);
}

// ---------------- launch ----------------

extern "C" void kernel_launch(void* const* d_in, const int* in_sizes, int n_in,
                              void* d_out, int out_size, void* d_ws, size_t ws_size,
                              hipStream_t stream) {
    const float* x   = (const float*)d_in[0];
    const int*   ei  = (const int*)d_in[1];
    const float* We  = (const float*)d_in[2];
    const float* be  = (const float*)d_in[3];
    const float* W1  = (const float*)d_in[4];
    const float* b1  = (const float*)d_in[5];
    const float* g1  = (const float*)d_in[6];
    const float* bt1 = (const float*)d_in[7];
    const float* W2  = (const float*)d_in[8];
    const float* b2  = (const float*)d_in[9];
    const float* g2  = (const float*)d_in[10];
    const float* bt2 = (const float*)d_in[11];
    const float* W3  = (const float*)d_in[12];
    const float* b3  = (const float*)d_in[13];
    const float* g3  = (const float*)d_in[14];
    const float* bt3 = (const float*)d_in[15];
    const float* Wf1 = (const float*)d_in[16];
    const float* bf1 = (const float*)d_in[17];
    const float* gf  = (const float*)d_in[18];
    const float* btf = (const float*)d_in[19];
    const float* Wf2 = (const float*)d_in[20];
    const float* bf2 = (const float*)d_in[21];
    float* out = (float*)d_out;

    const int n = in_sizes[0] / 2;      // x is [N,2]
    const int e = in_sizes[1] / 2;      // edge_index is [2,E]
    const int* srcp = ei;
    const int* dstp = ei + e;
    const int nbk = (n + BK - 1) / BK;  // 1563 for n=1e5 (<= MAXNBK)

    char* p = (char*)d_ws;
    auto alloc = [&](size_t bytes) { void* r = (void*)p; p += (bytes + 255) & ~(size_t)255; return r; };
    int*   bcount = (int*)alloc((size_t)nbk * 16 * 4);
    int*   boffs  = (int*)alloc((size_t)(nbk + 1) * 4);
    int*   bcur   = (int*)alloc((size_t)nbk * 16 * 4);
    int*   btmp   = (int*)alloc((size_t)e * 4);
    float* dinv   = (float*)alloc((size_t)n * 4);
    float* h      = (float*)alloc((size_t)n * HID * 4);
    float* t      = (float*)alloc((size_t)n * HID * 4);
    float* agg    = (float*)alloc((size_t)n * HID * 4);
    float* bnS    = (float*)alloc(HID * 4);
    float* bnSS   = (float*)alloc(HID * 4);
    float* bnA    = (float*)alloc(HID * 4);
    float* bnC    = (float*)alloc(HID * 4);
    float* tf     = t;  // alias: t is dead by head stage

    hipMemsetAsync(bcount, 0, (size_t)nbk * 16 * 4, stream);
    k_bhist<<<(e + 4095) / 4096, 256, 0, stream>>>(dstp, bcount, e, nbk);
    k_bscan<<<1, 1024, 0, stream>>>(bcount, boffs, bcur, nbk, e);
    k_bscatter<<<256, 1024, 0, stream>>>(srcp, dstp, bcur, btmp, e, nbk);
    k_bdinv<<<nbk, 256, 0, stream>>>(btmp, boffs, dinv, n);
    k_embed<<<(n * HID + 255) / 256, 256, 0, stream>>>(x, We, be, h, n);

    const float* Wl[3]  = {W1, W2, W3};
    const float* bl[3]  = {b1, b2, b3};
    const float* gl[3]  = {g1, g2, g3};
    const float* btl[3] = {bt1, bt2, bt3};
    for (int L = 0; L < 3; ++L) {
        k_gemm128<<<(n + 63) / 64, 256, 0, stream>>>(h, Wl[L], dinv, t, n);
        k_agg2<<<nbk, 256, 0, stream>>>(t, btmp, boffs, dinv, bl[L], agg, n);
        hipMemsetAsync(bnS, 0, HID * 4, stream);
        hipMemsetAsync(bnSS, 0, HID * 4, stream);
        k_bn_stats128<<<512, 128, 0, stream>>>(agg, bnS, bnSS, n);
        k_bn_finalize<<<1, 128, 0, stream>>>(bnS, bnSS, gl[L], btl[L], bnA, bnC, n, 128);
        k_bn_apply_res<<<(n * HID + 255) / 256, 256, 0, stream>>>(agg, bnA, bnC, h, n * HID);
    }

    k_gemmf<<<(n + 63) / 64, 256, 0, stream>>>(h, Wf1, bf1, tf, n);
    hipMemsetAsync(bnS, 0, 32 * 4, stream);
    hipMemsetAsync(bnSS, 0, 32 * 4, stream);
    k_bn_stats32<<<512, 128, 0, stream>>>(tf, bnS, bnSS, n);
    k_bn_finalize<<<1, 32, 0, stream>>>(bnS, bnSS, gf, btf, bnA, bnC, n, 32);
    k_final<<<(n + 255) / 256, 256, 0, stream>>>(tf, bnA, bnC, Wf2, bf2, out, n);
}

// Round 5
// 1120.802 us; speedup vs baseline: 3.8406x; 3.8406x over previous
//
#include <hip/hip_runtime.h>
#include <math.h>

#define HID 128
#define EPS 1e-5f
#define BK 64          // dst nodes per bucket
#define MAXNBK 2048    // supports n <= 131072

// ---------------- bucketed graph preprocessing ----------------
// btmp entry: (src << 6) | (dst & 63)  -- src < 2^26 required (n=1e5 ok)

// per-block LDS histogram of dst buckets -> global bcount (padded *16 = one line each)
__global__ __launch_bounds__(256) void k_bhist(const int* __restrict__ dst, int* __restrict__ bcount,
                                               int e, int nbk) {
    __shared__ int hist[MAXNBK];
    for (int i = threadIdx.x; i < nbk; i += 256) hist[i] = 0;
    __syncthreads();
    int base = blockIdx.x * 4096;
    int end = min(base + 4096, e);
    for (int i = base + threadIdx.x; i < end; i += 256) atomicAdd(&hist[dst[i] >> 6], 1);
    __syncthreads();
    for (int i = threadIdx.x; i < nbk; i += 256) {
        int c = hist[i];
        if (c) atomicAdd(&bcount[i * 16], c);
    }
}

// single-block exclusive scan of bcount -> boffs[nbk+1], init bcur = boffs (padded)
__global__ __launch_bounds__(1024) void k_bscan(const int* __restrict__ bcount, int* __restrict__ boffs,
                                                int* __restrict__ bcur, int nbk, int e) {
    __shared__ int lds[1024];
    int tid = threadIdx.x;
    int i0 = 2 * tid, i1 = 2 * tid + 1;
    int a = (i0 < nbk) ? bcount[i0 * 16] : 0;
    int b = (i1 < nbk) ? bcount[i1 * 16] : 0;
    lds[tid] = a + b;
    __syncthreads();
    for (int off = 1; off < 1024; off <<= 1) {
        int v = (tid >= off) ? lds[tid - off] : 0;
        __syncthreads();
        lds[tid] += v;
        __syncthreads();
    }
    int excl = lds[tid] - (a + b);
    if (i0 < nbk) { boffs[i0] = excl;     bcur[i0 * 16] = excl; }
    if (i1 < nbk) { boffs[i1] = excl + a; bcur[i1 * 16] = excl + a; }
    if (tid == 1023) boffs[nbk] = e;
}

// scatter edges into bucket-grouped btmp; per-(block,bucket) contiguous runs
__global__ __launch_bounds__(1024) void k_bscatter(const int* __restrict__ src, const int* __restrict__ dst,
                                                   int* __restrict__ bcur, int* __restrict__ btmp,
                                                   int e, int nbk) {
    __shared__ int hist[MAXNBK];
    int tid = threadIdx.x;
    for (int i = tid; i < nbk; i += 1024) hist[i] = 0;
    __syncthreads();
    int per = (e + gridDim.x - 1) / gridDim.x;
    int base = blockIdx.x * per;
    int end = min(base + per, e);
    for (int i = base + tid; i < end; i += 1024) atomicAdd(&hist[dst[i] >> 6], 1);
    __syncthreads();
    for (int i = tid; i < nbk; i += 1024) {
        int c = hist[i];
        hist[i] = c ? atomicAdd(&bcur[i * 16], c) : 0;  // hist := global base of this block's run
    }
    __syncthreads();
    for (int i = base + tid; i < end; i += 1024) {
        int d = dst[i];
        int pos = atomicAdd(&hist[d >> 6], 1);          // LDS int atomic -> global slot
        btmp[pos] = (src[i] << 6) | (d & 63);
    }
}

// per-bucket counting sort: btmp (bucket-grouped) -> csr (dst-sorted src ids),
// plus per-node offs and dinv. All int LDS atomics (native ds_add_u32).
__global__ __launch_bounds__(256) void k_bsort(const int* __restrict__ btmp, const int* __restrict__ boffs,
                                               int* __restrict__ csr, int* __restrict__ offs,
                                               float* __restrict__ dinv, int n, int etot) {
    __shared__ int cnt[BK];
    __shared__ int cur[BK];
    int b = blockIdx.x, tid = threadIdx.x;
    if (tid < BK) cnt[tid] = 0;
    __syncthreads();
    int e0 = boffs[b], e1 = boffs[b + 1];
    for (int i = e0 + tid; i < e1; i += 256) atomicAdd(&cnt[btmp[i] & 63], 1);
    __syncthreads();
    if (tid == 0) {
        int run = 0;
        for (int d = 0; d < BK; ++d) { cur[d] = run; run += cnt[d]; }
    }
    __syncthreads();
    if (tid < BK) {
        int node = b * BK + tid;
        if (node < n) {
            offs[node] = e0 + cur[tid];
            dinv[node] = rsqrtf((float)(cnt[tid] + 1));  // +1 self-loop
        }
    }
    if (b == 0 && tid == 0) offs[n] = etot;
    __syncthreads();
    for (int i = e0 + tid; i < e1; i += 256) {
        int p = btmp[i];
        int pos = e0 + atomicAdd(&cur[p & 63], 1);
        csr[pos] = p >> 6;
    }
}

// ---------------- embed: h = relu(x @ We + be), x is [N,2] ----------------

__global__ void k_embed(const float* __restrict__ x, const float* __restrict__ We,
                        const float* __restrict__ be, float* __restrict__ h, int n) {
    int i = blockIdx.x * 256 + threadIdx.x;
    if (i >= n * HID) return;
    int node = i >> 7, j = i & 127;
    float v = x[2 * node] * We[j] + x[2 * node + 1] * We[HID + j] + be[j];
    h[i] = fmaxf(v, 0.f);
}

// ---------------- GEMM: t'[n][j] = dinv[n] * sum_k h[n][k] * W[k][j], 128x128 ---------

__global__ __launch_bounds__(256) void k_gemm128(const float* __restrict__ h, const float* __restrict__ W,
                                                 const float* __restrict__ dinv,
                                                 float* __restrict__ out, int n) {
    __shared__ float hs[128][66];
    __shared__ float ws[128][64];
    int tid = threadIdx.x;
    int nb = blockIdx.x * 64;
    const float4* h4 = (const float4*)h;
#pragma unroll
    for (int r = 0; r < 8; ++r) {
        int idx = r * 256 + tid;
        int ni = idx >> 5;
        int k4 = idx & 31;
        int node = nb + ni;
        float4 v = make_float4(0.f, 0.f, 0.f, 0.f);
        if (node < n) v = h4[(size_t)node * 32 + k4];
        hs[k4 * 4 + 0][ni] = v.x; hs[k4 * 4 + 1][ni] = v.y;
        hs[k4 * 4 + 2][ni] = v.z; hs[k4 * 4 + 3][ni] = v.w;
    }
    int fg = tid & 15, ng = tid >> 4;
    const float4* w4 = (const float4*)W;
    for (int c = 0; c < 2; ++c) {
        if (c) __syncthreads();
#pragma unroll
        for (int r = 0; r < 8; ++r) {
            int idx = r * 256 + tid;
            int k = idx >> 4, f4 = idx & 15;
            *((float4*)&ws[k][f4 * 4]) = w4[k * 32 + c * 16 + f4];
        }
        __syncthreads();
        float acc[4][4] = {{0.f}};
#pragma unroll 8
        for (int k = 0; k < 128; ++k) {
            float2 a0 = *((const float2*)&hs[k][ng * 4]);
            float2 a1 = *((const float2*)&hs[k][ng * 4 + 2]);
            float4 w = *((const float4*)&ws[k][fg * 4]);
            float av[4] = {a0.x, a0.y, a1.x, a1.y};
            float wv[4] = {w.x, w.y, w.z, w.w};
#pragma unroll
            for (int i = 0; i < 4; ++i)
#pragma unroll
                for (int j = 0; j < 4; ++j)
                    acc[i][j] += av[i] * wv[j];
        }
#pragma unroll
        for (int i = 0; i < 4; ++i) {
            int node = nb + ng * 4 + i;
            if (node < n) {
                float dv = dinv[node];
                *((float4*)&out[(size_t)node * 128 + c * 64 + fg * 4]) =
                    make_float4(acc[i][0] * dv, acc[i][1] * dv, acc[i][2] * dv, acc[i][3] * dv);
            }
        }
    }
}

// ---------------- aggregation: out[i] = dinv[i]*(t'[i] + sum_{s in N(i)} t'[s]) + b ----
// One wave per node, lane = feature pair. Edge loop unrolled x8 for MLP.
// NO float LDS atomics (CAS-loop poison, round-4 lesson).

__global__ __launch_bounds__(256) void k_agg(const float* __restrict__ t, const int* __restrict__ offs,
                                             const int* __restrict__ csr, const float* __restrict__ dinv,
                                             const float* __restrict__ bias, float* __restrict__ out, int n) {
    int lane = threadIdx.x & 63;
    int node = blockIdx.x * 4 + (threadIdx.x >> 6);
    if (node >= n) return;
    const float2* t2 = (const float2*)t;
    float2 v = t2[(size_t)node * 64 + lane];
    float ax = v.x, ay = v.y;
    int e0 = offs[node], e1 = offs[node + 1];
    int e = e0;
    for (; e + 8 <= e1; e += 8) {
        int s0 = csr[e + 0], s1 = csr[e + 1], s2 = csr[e + 2], s3 = csr[e + 3];
        int s4 = csr[e + 4], s5 = csr[e + 5], s6 = csr[e + 6], s7 = csr[e + 7];
        float2 u0 = t2[(size_t)s0 * 64 + lane];
        float2 u1 = t2[(size_t)s1 * 64 + lane];
        float2 u2 = t2[(size_t)s2 * 64 + lane];
        float2 u3 = t2[(size_t)s3 * 64 + lane];
        float2 u4 = t2[(size_t)s4 * 64 + lane];
        float2 u5 = t2[(size_t)s5 * 64 + lane];
        float2 u6 = t2[(size_t)s6 * 64 + lane];
        float2 u7 = t2[(size_t)s7 * 64 + lane];
        ax += ((u0.x + u1.x) + (u2.x + u3.x)) + ((u4.x + u5.x) + (u6.x + u7.x));
        ay += ((u0.y + u1.y) + (u2.y + u3.y)) + ((u4.y + u5.y) + (u6.y + u7.y));
    }
    if (e + 4 <= e1) {
        int s0 = csr[e + 0], s1 = csr[e + 1], s2 = csr[e + 2], s3 = csr[e + 3];
        float2 u0 = t2[(size_t)s0 * 64 + lane];
        float2 u1 = t2[(size_t)s1 * 64 + lane];
        float2 u2 = t2[(size_t)s2 * 64 + lane];
        float2 u3 = t2[(size_t)s3 * 64 + lane];
        ax += (u0.x + u1.x) + (u2.x + u3.x);
        ay += (u0.y + u1.y) + (u2.y + u3.y);
        e += 4;
    }
    for (; e < e1; ++e) {
        int s = csr[e];
        float2 u = t2[(size_t)s * 64 + lane];
        ax += u.x; ay += u.y;
    }
    float di = dinv[node];
    float2 b = ((const float2*)bias)[lane];
    ((float2*)out)[(size_t)node * 64 + lane] = make_float2(ax * di + b.x, ay * di + b.y);
}

// ---------------- BN ----------------

__global__ void k_bn_stats128(const float* __restrict__ v, float* __restrict__ S,
                              float* __restrict__ SS, int n) {
    int j = threadIdx.x;  // 128 threads
    int per = (n + gridDim.x - 1) / gridDim.x;
    int start = blockIdx.x * per;
    int end = min(start + per, n);
    float s = 0.f, ss = 0.f;
    for (int i = start; i < end; ++i) {
        float x = v[(size_t)i * 128 + j];
        s += x; ss += x * x;
    }
    atomicAdd(&S[j], s);
    atomicAdd(&SS[j], ss);
}

__global__ void k_bn_stats32(const float* __restrict__ v, float* __restrict__ S,
                             float* __restrict__ SS, int n) {
    int j = threadIdx.x & 31, sub = threadIdx.x >> 5;
    int per = (n + gridDim.x - 1) / gridDim.x;
    int start = blockIdx.x * per;
    int end = min(start + per, n);
    float s = 0.f, ss = 0.f;
    for (int i = start + sub; i < end; i += 4) {
        float x = v[(size_t)i * 32 + j];
        s += x; ss += x * x;
    }
    atomicAdd(&S[j], s);
    atomicAdd(&SS[j], ss);
}

__global__ void k_bn_finalize(const float* __restrict__ S, const float* __restrict__ SS,
                              const float* __restrict__ g, const float* __restrict__ bt,
                              float* __restrict__ A, float* __restrict__ C, int n, int hid) {
    int j = threadIdx.x;
    if (j >= hid) return;
    float mu = S[j] / (float)n;
    float var = SS[j] / (float)n - mu * mu;
    float inv = rsqrtf(var + EPS);
    A[j] = g[j] * inv;
    C[j] = bt[j] - mu * g[j] * inv;
}

// h[i] = relu(agg[i]*A + C) + h[i]
__global__ void k_bn_apply_res(const float* __restrict__ agg, const float* __restrict__ A,
                               const float* __restrict__ C, float* __restrict__ h, int total) {
    int i = blockIdx.x * 256 + threadIdx.x;
    if (i < total) {
        int j = i & 127;
        float v = agg[i] * A[j] + C[j];
        h[i] += fmaxf(v, 0.f);
    }
}

// ---------------- head GEMM: tf = h @ Wf1 + bf1 (128 -> 32) ----------------

__global__ __launch_bounds__(256) void k_gemmf(const float* __restrict__ h, const float* __restrict__ W,
                                               const float* __restrict__ bias, float* __restrict__ out, int n) {
    __shared__ float hs[128][66];
    __shared__ float ws[128][32];
    int tid = threadIdx.x;
    int nb = blockIdx.x * 64;
    const float4* h4 = (const float4*)h;
#pragma unroll
    for (int r = 0; r < 8; ++r) {
        int idx = r * 256 + tid;
        int ni = idx >> 5, k4 = idx & 31;
        int node = nb + ni;
        float4 v = make_float4(0.f, 0.f, 0.f, 0.f);
        if (node < n) v = h4[(size_t)node * 32 + k4];
        hs[k4 * 4 + 0][ni] = v.x; hs[k4 * 4 + 1][ni] = v.y;
        hs[k4 * 4 + 2][ni] = v.z; hs[k4 * 4 + 3][ni] = v.w;
    }
    const float4* w4 = (const float4*)W;
#pragma unroll
    for (int r = 0; r < 4; ++r) {
        int idx = r * 256 + tid;
        int k = idx >> 3, f4 = idx & 7;
        *((float4*)&ws[k][f4 * 4]) = w4[k * 8 + f4];
    }
    __syncthreads();
    int fg = tid & 7, ng = tid >> 3;
    float acc[2][4] = {{0.f}};
#pragma unroll 8
    for (int k = 0; k < 128; ++k) {
        float2 a = *((const float2*)&hs[k][ng * 2]);
        float4 w = *((const float4*)&ws[k][fg * 4]);
        acc[0][0] += a.x * w.x; acc[0][1] += a.x * w.y; acc[0][2] += a.x * w.z; acc[0][3] += a.x * w.w;
        acc[1][0] += a.y * w.x; acc[1][1] += a.y * w.y; acc[1][2] += a.y * w.z; acc[1][3] += a.y * w.w;
    }
    float4 bb = *((const float4*)&bias[fg * 4]);
#pragma unroll
    for (int i = 0; i < 2; ++i) {
        int node = nb + ng * 2 + i;
        if (node < n)
            *((float4*)&out[(size_t)node * 32 + fg * 4]) =
                make_float4(acc[i][0] + bb.x, acc[i][1] + bb.y, acc[i][2] + bb.z, acc[i][3] + bb.w);
    }
}

// ---------------- final: out = tanh(relu(bn(tf)) @ Wf2 + bf2) ----------------

__global__ void k_final(const float* __restrict__ tf, const float* __restrict__ A,
                        const float* __restrict__ C, const float* __restrict__ Wf2,
                        const float* __restrict__ bf2, float* __restrict__ out, int n) {
    int node = blockIdx.x * 256 + threadIdx.x;
    if (node >= n) return;
    float o0 = bf2[0], o1 = bf2[1];
    const float4* t4 = (const float4*)(tf + (size_t)node * 32);
#pragma unroll
    for (int q = 0; q < 8; ++q) {
        float4 v = t4[q];
        float vv[4] = {v.x, v.y, v.z, v.w};
#pragma unroll
        for (int r = 0; r < 4; ++r) {
            int j = q * 4 + r;
            float f = fmaxf(vv[r] * A[j] + C[j], 0.f);
            o0 += f * Wf2[2 * j];
            o1 += f * Wf2[2 * j + 1];
        }
    }
    out[2 * node] = tanhf(o0);
    out[2 * node + 1] = tanhf(o1);
}

// ---------------- launch ----------------

extern "C" void kernel_launch(void* const* d_in, const int* in_sizes, int n_in,
                              void* d_out, int out_size, void* d_ws, size_t ws_size,
                              hipStream_t stream) {
    const float* x   = (const float*)d_in[0];
    const int*   ei  = (const int*)d_in[1];
    const float* We  = (const float*)d_in[2];
    const float* be  = (const float*)d_in[3];
    const float* W1  = (const float*)d_in[4];
    const float* b1  = (const float*)d_in[5];
    const float* g1  = (const float*)d_in[6];
    const float* bt1 = (const float*)d_in[7];
    const float* W2  = (const float*)d_in[8];
    const float* b2  = (const float*)d_in[9];
    const float* g2  = (const float*)d_in[10];
    const float* bt2 = (const float*)d_in[11];
    const float* W3  = (const float*)d_in[12];
    const float* b3  = (const float*)d_in[13];
    const float* g3  = (const float*)d_in[14];
    const float* bt3 = (const float*)d_in[15];
    const float* Wf1 = (const float*)d_in[16];
    const float* bf1 = (const float*)d_in[17];
    const float* gf  = (const float*)d_in[18];
    const float* btf = (const float*)d_in[19];
    const float* Wf2 = (const float*)d_in[20];
    const float* bf2 = (const float*)d_in[21];
    float* out = (float*)d_out;

    const int n = in_sizes[0] / 2;      // x is [N,2]
    const int e = in_sizes[1] / 2;      // edge_index is [2,E]
    const int* srcp = ei;
    const int* dstp = ei + e;
    const int nbk = (n + BK - 1) / BK;  // 1563 for n=1e5 (<= MAXNBK)

    char* p = (char*)d_ws;
    auto alloc = [&](size_t bytes) { void* r = (void*)p; p += (bytes + 255) & ~(size_t)255; return r; };
    int*   bcount = (int*)alloc((size_t)nbk * 16 * 4);
    int*   boffs  = (int*)alloc((size_t)(nbk + 1) * 4);
    int*   bcur   = (int*)alloc((size_t)nbk * 16 * 4);
    int*   btmp   = (int*)alloc((size_t)e * 4);
    int*   csr    = (int*)alloc((size_t)e * 4);
    int*   offs   = (int*)alloc((size_t)(n + 1) * 4);
    float* dinv   = (float*)alloc((size_t)n * 4);
    float* h      = (float*)alloc((size_t)n * HID * 4);
    float* t      = (float*)alloc((size_t)n * HID * 4);
    float* agg    = (float*)alloc((size_t)n * HID * 4);
    float* bnS    = (float*)alloc(HID * 4);
    float* bnSS   = (float*)alloc(HID * 4);
    float* bnA    = (float*)alloc(HID * 4);
    float* bnC    = (float*)alloc(HID * 4);
    float* tf     = t;  // alias: t is dead by head stage

    hipMemsetAsync(bcount, 0, (size_t)nbk * 16 * 4, stream);
    k_bhist<<<(e + 4095) / 4096, 256, 0, stream>>>(dstp, bcount, e, nbk);
    k_bscan<<<1, 1024, 0, stream>>>(bcount, boffs, bcur, nbk, e);
    k_bscatter<<<256, 1024, 0, stream>>>(srcp, dstp, bcur, btmp, e, nbk);
    k_bsort<<<nbk, 256, 0, stream>>>(btmp, boffs, csr, offs, dinv, n, e);
    k_embed<<<(n * HID + 255) / 256, 256, 0, stream>>>(x, We, be, h, n);

    const float* Wl[3]  = {W1, W2, W3};
    const float* bl[3]  = {b1, b2, b3};
    const float* gl[3]  = {g1, g2, g3};
    const float* btl[3] = {bt1, bt2, bt3};
    for (int L = 0; L < 3; ++L) {
        k_gemm128<<<(n + 63) / 64, 256, 0, stream>>>(h, Wl[L], dinv, t, n);
        k_agg<<<(n + 3) / 4, 256, 0, stream>>>(t, offs, csr, dinv, bl[L], agg, n);
        hipMemsetAsync(bnS, 0, HID * 4, stream);
        hipMemsetAsync(bnSS, 0, HID * 4, stream);
        k_bn_stats128<<<512, 128, 0, stream>>>(agg, bnS, bnSS, n);
        k_bn_finalize<<<1, 128, 0, stream>>>(bnS, bnSS, gl[L], btl[L], bnA, bnC, n, 128);
        k_bn_apply_res<<<(n * HID + 255) / 256, 256, 0, stream>>>(agg, bnA, bnC, h, n * HID);
    }

    k_gemmf<<<(n + 63) / 64, 256, 0, stream>>>(h, Wf1, bf1, tf, n);
    hipMemsetAsync(bnS, 0, 32 * 4, stream);
    hipMemsetAsync(bnSS, 0, 32 * 4, stream);
    k_bn_stats32<<<512, 128, 0, stream>>>(tf, bnS, bnSS, n);
    k_bn_finalize<<<1, 32, 0, stream>>>(bnS, bnSS, gf, btf, bnA, bnC, n, 32);
    k_final<<<(n + 255) / 256, 256, 0, stream>>>(tf, bnA, bnC, Wf2, bf2, out, n);
}

// Round 6
// 902.613 us; speedup vs baseline: 4.7690x; 1.2417x over previous
//
#include <hip/hip_runtime.h>
#include <hip/hip_fp16.h>
#include <math.h>

#define HID 128
#define EPS 1e-5f
#define BK 64          // dst nodes per bucket
#define MAXNBK 2048    // supports n <= 131072

// ---------------- bucketed graph preprocessing ----------------
// btmp entry: (src << 6) | (dst & 63)  -- src < 2^26 required (n=1e5 ok)

__global__ __launch_bounds__(256) void k_bhist(const int* __restrict__ dst, int* __restrict__ bcount,
                                               int e, int nbk) {
    __shared__ int hist[MAXNBK];
    for (int i = threadIdx.x; i < nbk; i += 256) hist[i] = 0;
    __syncthreads();
    int base = blockIdx.x * 4096;
    int end = min(base + 4096, e);
    for (int i = base + threadIdx.x; i < end; i += 256) atomicAdd(&hist[dst[i] >> 6], 1);
    __syncthreads();
    for (int i = threadIdx.x; i < nbk; i += 256) {
        int c = hist[i];
        if (c) atomicAdd(&bcount[i * 16], c);
    }
}

__global__ __launch_bounds__(1024) void k_bscan(const int* __restrict__ bcount, int* __restrict__ boffs,
                                                int* __restrict__ bcur, int nbk, int e) {
    __shared__ int lds[1024];
    int tid = threadIdx.x;
    int i0 = 2 * tid, i1 = 2 * tid + 1;
    int a = (i0 < nbk) ? bcount[i0 * 16] : 0;
    int b = (i1 < nbk) ? bcount[i1 * 16] : 0;
    lds[tid] = a + b;
    __syncthreads();
    for (int off = 1; off < 1024; off <<= 1) {
        int v = (tid >= off) ? lds[tid - off] : 0;
        __syncthreads();
        lds[tid] += v;
        __syncthreads();
    }
    int excl = lds[tid] - (a + b);
    if (i0 < nbk) { boffs[i0] = excl;     bcur[i0 * 16] = excl; }
    if (i1 < nbk) { boffs[i1] = excl + a; bcur[i1 * 16] = excl + a; }
    if (tid == 1023) boffs[nbk] = e;
}

__global__ __launch_bounds__(1024) void k_bscatter(const int* __restrict__ src, const int* __restrict__ dst,
                                                   int* __restrict__ bcur, int* __restrict__ btmp,
                                                   int e, int nbk) {
    __shared__ int hist[MAXNBK];
    int tid = threadIdx.x;
    for (int i = tid; i < nbk; i += 1024) hist[i] = 0;
    __syncthreads();
    int per = (e + gridDim.x - 1) / gridDim.x;
    int base = blockIdx.x * per;
    int end = min(base + per, e);
    for (int i = base + tid; i < end; i += 1024) atomicAdd(&hist[dst[i] >> 6], 1);
    __syncthreads();
    for (int i = tid; i < nbk; i += 1024) {
        int c = hist[i];
        hist[i] = c ? atomicAdd(&bcur[i * 16], c) : 0;
    }
    __syncthreads();
    for (int i = base + tid; i < end; i += 1024) {
        int d = dst[i];
        int pos = atomicAdd(&hist[d >> 6], 1);          // LDS int atomic (native)
        btmp[pos] = (src[i] << 6) | (d & 63);
    }
}

// per-bucket counting sort: btmp -> csr (dst-sorted src ids) + offs + dinv (int LDS atomics only)
__global__ __launch_bounds__(256) void k_bsort(const int* __restrict__ btmp, const int* __restrict__ boffs,
                                               int* __restrict__ csr, int* __restrict__ offs,
                                               float* __restrict__ dinv, int n, int etot) {
    __shared__ int cnt[BK];
    __shared__ int cur[BK];
    int b = blockIdx.x, tid = threadIdx.x;
    if (tid < BK) cnt[tid] = 0;
    __syncthreads();
    int e0 = boffs[b], e1 = boffs[b + 1];
    for (int i = e0 + tid; i < e1; i += 256) atomicAdd(&cnt[btmp[i] & 63], 1);
    __syncthreads();
    if (tid == 0) {
        int run = 0;
        for (int d = 0; d < BK; ++d) { cur[d] = run; run += cnt[d]; }
    }
    __syncthreads();
    if (tid < BK) {
        int node = b * BK + tid;
        if (node < n) {
            offs[node] = e0 + cur[tid];
            dinv[node] = rsqrtf((float)(cnt[tid] + 1));  // +1 self-loop
        }
    }
    if (b == 0 && tid == 0) offs[n] = etot;
    __syncthreads();
    for (int i = e0 + tid; i < e1; i += 256) {
        int p = btmp[i];
        int pos = e0 + atomicAdd(&cur[p & 63], 1);
        csr[pos] = p >> 6;
    }
}

// ---------------- embed: h = relu(x @ We + be), x is [N,2] ----------------

__global__ void k_embed(const float* __restrict__ x, const float* __restrict__ We,
                        const float* __restrict__ be, float* __restrict__ h, int n) {
    int i = blockIdx.x * 256 + threadIdx.x;
    if (i >= n * HID) return;
    int node = i >> 7, j = i & 127;
    float v = x[2 * node] * We[j] + x[2 * node + 1] * We[HID + j] + be[j];
    h[i] = fmaxf(v, 0.f);
}

// ---------------- GEMM: th[n][j] = fp16( dinv[n] * sum_k h[n][k] * W[k][j] ) ----------

__global__ __launch_bounds__(256) void k_gemm128(const float* __restrict__ h, const float* __restrict__ W,
                                                 const float* __restrict__ dinv,
                                                 __half2* __restrict__ th, int n) {
    __shared__ float hs[128][66];
    __shared__ float ws[128][64];
    int tid = threadIdx.x;
    int nb = blockIdx.x * 64;
    const float4* h4 = (const float4*)h;
#pragma unroll
    for (int r = 0; r < 8; ++r) {
        int idx = r * 256 + tid;
        int ni = idx >> 5;
        int k4 = idx & 31;
        int node = nb + ni;
        float4 v = make_float4(0.f, 0.f, 0.f, 0.f);
        if (node < n) v = h4[(size_t)node * 32 + k4];
        hs[k4 * 4 + 0][ni] = v.x; hs[k4 * 4 + 1][ni] = v.y;
        hs[k4 * 4 + 2][ni] = v.z; hs[k4 * 4 + 3][ni] = v.w;
    }
    int fg = tid & 15, ng = tid >> 4;
    const float4* w4 = (const float4*)W;
    for (int c = 0; c < 2; ++c) {
        if (c) __syncthreads();
#pragma unroll
        for (int r = 0; r < 8; ++r) {
            int idx = r * 256 + tid;
            int k = idx >> 4, f4 = idx & 15;
            *((float4*)&ws[k][f4 * 4]) = w4[k * 32 + c * 16 + f4];
        }
        __syncthreads();
        float acc[4][4] = {{0.f}};
#pragma unroll 8
        for (int k = 0; k < 128; ++k) {
            float2 a0 = *((const float2*)&hs[k][ng * 4]);
            float2 a1 = *((const float2*)&hs[k][ng * 4 + 2]);
            float4 w = *((const float4*)&ws[k][fg * 4]);
            float av[4] = {a0.x, a0.y, a1.x, a1.y};
            float wv[4] = {w.x, w.y, w.z, w.w};
#pragma unroll
            for (int i = 0; i < 4; ++i)
#pragma unroll
                for (int j = 0; j < 4; ++j)
                    acc[i][j] += av[i] * wv[j];
        }
#pragma unroll
        for (int i = 0; i < 4; ++i) {
            int node = nb + ng * 4 + i;
            if (node < n) {
                float dv = dinv[node];
                union { __half2 hh[2]; float2 f; } pk;
                pk.hh[0] = __floats2half2_rn(acc[i][0] * dv, acc[i][1] * dv);
                pk.hh[1] = __floats2half2_rn(acc[i][2] * dv, acc[i][3] * dv);
                ((float2*)th)[((size_t)node * 128 + c * 64 + fg * 4) >> 2] = pk.f;
            }
        }
    }
}

// ---------------- aggregation + fused BN stats ---------------------------------------
// out[i] = dinv[i]*(th[i] + sum th[s]) + b  (th fp16, accum fp32)
// Grid-stride over 4-node groups; per-thread feature-fixed running sums -> LDS -> global
// float atomics (1024 blocks => ~1k atomics/address, proven-OK scale; NO float LDS atomics).

__global__ __launch_bounds__(256) void k_agg(const __half2* __restrict__ t, const int* __restrict__ offs,
                                             const int* __restrict__ csr, const float* __restrict__ dinv,
                                             const float* __restrict__ bias, float* __restrict__ out,
                                             float* __restrict__ S, float* __restrict__ SS, int n) {
    __shared__ float ls[4][128];
    __shared__ float lss[4][128];
    int tid = threadIdx.x;
    int lane = tid & 63, w = tid >> 6;
    float2 b = ((const float2*)bias)[lane];
    float sx = 0.f, sy = 0.f, qx = 0.f, qy = 0.f;
    int ngrp = (n + 3) >> 2;
    for (int grp = blockIdx.x; grp < ngrp; grp += gridDim.x) {
        int node = grp * 4 + w;
        if (node < n) {
            float2 vf = __half22float2(t[(size_t)node * 64 + lane]);
            float ax = vf.x, ay = vf.y;
            int e0 = offs[node], e1 = offs[node + 1];
            int e = e0;
            for (; e + 8 <= e1; e += 8) {
                int s0 = csr[e + 0], s1 = csr[e + 1], s2 = csr[e + 2], s3 = csr[e + 3];
                int s4 = csr[e + 4], s5 = csr[e + 5], s6 = csr[e + 6], s7 = csr[e + 7];
                float2 u0 = __half22float2(t[(size_t)s0 * 64 + lane]);
                float2 u1 = __half22float2(t[(size_t)s1 * 64 + lane]);
                float2 u2 = __half22float2(t[(size_t)s2 * 64 + lane]);
                float2 u3 = __half22float2(t[(size_t)s3 * 64 + lane]);
                float2 u4 = __half22float2(t[(size_t)s4 * 64 + lane]);
                float2 u5 = __half22float2(t[(size_t)s5 * 64 + lane]);
                float2 u6 = __half22float2(t[(size_t)s6 * 64 + lane]);
                float2 u7 = __half22float2(t[(size_t)s7 * 64 + lane]);
                ax += ((u0.x + u1.x) + (u2.x + u3.x)) + ((u4.x + u5.x) + (u6.x + u7.x));
                ay += ((u0.y + u1.y) + (u2.y + u3.y)) + ((u4.y + u5.y) + (u6.y + u7.y));
            }
            if (e + 4 <= e1) {
                int s0 = csr[e + 0], s1 = csr[e + 1], s2 = csr[e + 2], s3 = csr[e + 3];
                float2 u0 = __half22float2(t[(size_t)s0 * 64 + lane]);
                float2 u1 = __half22float2(t[(size_t)s1 * 64 + lane]);
                float2 u2 = __half22float2(t[(size_t)s2 * 64 + lane]);
                float2 u3 = __half22float2(t[(size_t)s3 * 64 + lane]);
                ax += (u0.x + u1.x) + (u2.x + u3.x);
                ay += (u0.y + u1.y) + (u2.y + u3.y);
                e += 4;
            }
            for (; e < e1; ++e) {
                float2 u = __half22float2(t[(size_t)csr[e] * 64 + lane]);
                ax += u.x; ay += u.y;
            }
            float di = dinv[node];
            float vx = ax * di + b.x, vy = ay * di + b.y;
            ((float2*)out)[(size_t)node * 64 + lane] = make_float2(vx, vy);
            sx += vx; sy += vy; qx += vx * vx; qy += vy * vy;
        }
    }
    ls[w][2 * lane] = sx;  ls[w][2 * lane + 1] = sy;
    lss[w][2 * lane] = qx; lss[w][2 * lane + 1] = qy;
    __syncthreads();
    if (tid < 128) {
        float s = ls[0][tid] + ls[1][tid] + ls[2][tid] + ls[3][tid];
        float q = lss[0][tid] + lss[1][tid] + lss[2][tid] + lss[3][tid];
        atomicAdd(&S[tid], s);
        atomicAdd(&SS[tid], q);
    }
}

// ---------------- BN ----------------

__global__ void k_bn_stats32(const float* __restrict__ v, float* __restrict__ S,
                             float* __restrict__ SS, int n) {
    int j = threadIdx.x & 31, sub = threadIdx.x >> 5;
    int per = (n + gridDim.x - 1) / gridDim.x;
    int start = blockIdx.x * per;
    int end = min(start + per, n);
    float s = 0.f, ss = 0.f;
    for (int i = start + sub; i < end; i += 4) {
        float x = v[(size_t)i * 32 + j];
        s += x; ss += x * x;
    }
    atomicAdd(&S[j], s);
    atomicAdd(&SS[j], ss);
}

__global__ void k_bn_finalize(const float* __restrict__ S, const float* __restrict__ SS,
                              const float* __restrict__ g, const float* __restrict__ bt,
                              float* __restrict__ A, float* __restrict__ C, int n, int hid) {
    int j = threadIdx.x;
    if (j >= hid) return;
    float mu = S[j] / (float)n;
    float var = SS[j] / (float)n - mu * mu;
    float inv = rsqrtf(var + EPS);
    A[j] = g[j] * inv;
    C[j] = bt[j] - mu * g[j] * inv;
}

// h[i] = relu(agg[i]*A + C) + h[i]
__global__ void k_bn_apply_res(const float* __restrict__ agg, const float* __restrict__ A,
                               const float* __restrict__ C, float* __restrict__ h, int total) {
    int i = blockIdx.x * 256 + threadIdx.x;
    if (i < total) {
        int j = i & 127;
        float v = agg[i] * A[j] + C[j];
        h[i] += fmaxf(v, 0.f);
    }
}

// ---------------- head GEMM: tf = h @ Wf1 + bf1 (128 -> 32) ----------------

__global__ __launch_bounds__(256) void k_gemmf(const float* __restrict__ h, const float* __restrict__ W,
                                               const float* __restrict__ bias, float* __restrict__ out, int n) {
    __shared__ float hs[128][66];
    __shared__ float ws[128][32];
    int tid = threadIdx.x;
    int nb = blockIdx.x * 64;
    const float4* h4 = (const float4*)h;
#pragma unroll
    for (int r = 0; r < 8; ++r) {
        int idx = r * 256 + tid;
        int ni = idx >> 5, k4 = idx & 31;
        int node = nb + ni;
        float4 v = make_float4(0.f, 0.f, 0.f, 0.f);
        if (node < n) v = h4[(size_t)node * 32 + k4];
        hs[k4 * 4 + 0][ni] = v.x; hs[k4 * 4 + 1][ni] = v.y;
        hs[k4 * 4 + 2][ni] = v.z; hs[k4 * 4 + 3][ni] = v.w;
    }
    const float4* w4 = (const float4*)W;
#pragma unroll
    for (int r = 0; r < 4; ++r) {
        int idx = r * 256 + tid;
        int k = idx >> 3, f4 = idx & 7;
        *((float4*)&ws[k][f4 * 4]) = w4[k * 8 + f4];
    }
    __syncthreads();
    int fg = tid & 7, ng = tid >> 3;
    float acc[2][4] = {{0.f}};
#pragma unroll 8
    for (int k = 0; k < 128; ++k) {
        float2 a = *((const float2*)&hs[k][ng * 2]);
        float4 w = *((const float4*)&ws[k][fg * 4]);
        acc[0][0] += a.x * w.x; acc[0][1] += a.x * w.y; acc[0][2] += a.x * w.z; acc[0][3] += a.x * w.w;
        acc[1][0] += a.y * w.x; acc[1][1] += a.y * w.y; acc[1][2] += a.y * w.z; acc[1][3] += a.y * w.w;
    }
    float4 bb = *((const float4*)&bias[fg * 4]);
#pragma unroll
    for (int i = 0; i < 2; ++i) {
        int node = nb + ng * 2 + i;
        if (node < n)
            *((float4*)&out[(size_t)node * 32 + fg * 4]) =
                make_float4(acc[i][0] + bb.x, acc[i][1] + bb.y, acc[i][2] + bb.z, acc[i][3] + bb.w);
    }
}

// ---------------- final: out = tanh(relu(bn(tf)) @ Wf2 + bf2) ----------------

__global__ void k_final(const float* __restrict__ tf, const float* __restrict__ A,
                        const float* __restrict__ C, const float* __restrict__ Wf2,
                        const float* __restrict__ bf2, float* __restrict__ out, int n) {
    int node = blockIdx.x * 256 + threadIdx.x;
    if (node >= n) return;
    float o0 = bf2[0], o1 = bf2[1];
    const float4* t4 = (const float4*)(tf + (size_t)node * 32);
#pragma unroll
    for (int q = 0; q < 8; ++q) {
        float4 v = t4[q];
        float vv[4] = {v.x, v.y, v.z, v.w};
#pragma unroll
        for (int r = 0; r < 4; ++r) {
            int j = q * 4 + r;
            float f = fmaxf(vv[r] * A[j] + C[j], 0.f);
            o0 += f * Wf2[2 * j];
            o1 += f * Wf2[2 * j + 1];
        }
    }
    out[2 * node] = tanhf(o0);
    out[2 * node + 1] = tanhf(o1);
}

// ---------------- launch ----------------

extern "C" void kernel_launch(void* const* d_in, const int* in_sizes, int n_in,
                              void* d_out, int out_size, void* d_ws, size_t ws_size,
                              hipStream_t stream) {
    const float* x   = (const float*)d_in[0];
    const int*   ei  = (const int*)d_in[1];
    const float* We  = (const float*)d_in[2];
    const float* be  = (const float*)d_in[3];
    const float* W1  = (const float*)d_in[4];
    const float* b1  = (const float*)d_in[5];
    const float* g1  = (const float*)d_in[6];
    const float* bt1 = (const float*)d_in[7];
    const float* W2  = (const float*)d_in[8];
    const float* b2  = (const float*)d_in[9];
    const float* g2  = (const float*)d_in[10];
    const float* bt2 = (const float*)d_in[11];
    const float* W3  = (const float*)d_in[12];
    const float* b3  = (const float*)d_in[13];
    const float* g3  = (const float*)d_in[14];
    const float* bt3 = (const float*)d_in[15];
    const float* Wf1 = (const float*)d_in[16];
    const float* bf1 = (const float*)d_in[17];
    const float* gf  = (const float*)d_in[18];
    const float* btf = (const float*)d_in[19];
    const float* Wf2 = (const float*)d_in[20];
    const float* bf2 = (const float*)d_in[21];
    float* out = (float*)d_out;

    const int n = in_sizes[0] / 2;      // x is [N,2]
    const int e = in_sizes[1] / 2;      // edge_index is [2,E]
    const int* srcp = ei;
    const int* dstp = ei + e;
    const int nbk = (n + BK - 1) / BK;

    char* p = (char*)d_ws;
    auto alloc = [&](size_t bytes) { void* r = (void*)p; p += (bytes + 255) & ~(size_t)255; return r; };
    int*     bcount = (int*)alloc((size_t)nbk * 16 * 4);
    int*     boffs  = (int*)alloc((size_t)(nbk + 1) * 4);
    int*     bcur   = (int*)alloc((size_t)nbk * 16 * 4);
    int*     btmp   = (int*)alloc((size_t)e * 4);
    int*     csr    = (int*)alloc((size_t)e * 4);
    int*     offs   = (int*)alloc((size_t)(n + 1) * 4);
    float*   dinv   = (float*)alloc((size_t)n * 4);
    float*   h      = (float*)alloc((size_t)n * HID * 4);
    __half2* th     = (__half2*)alloc((size_t)n * HID * 2);
    float*   agg    = (float*)alloc((size_t)n * HID * 4);
    float*   tf     = (float*)alloc((size_t)n * 32 * 4);
    float*   bnS    = (float*)alloc(HID * 4);
    float*   bnSS   = (float*)alloc(HID * 4);
    float*   bnA    = (float*)alloc(HID * 4);
    float*   bnC    = (float*)alloc(HID * 4);

    hipMemsetAsync(bcount, 0, (size_t)nbk * 16 * 4, stream);
    k_bhist<<<(e + 4095) / 4096, 256, 0, stream>>>(dstp, bcount, e, nbk);
    k_bscan<<<1, 1024, 0, stream>>>(bcount, boffs, bcur, nbk, e);
    k_bscatter<<<256, 1024, 0, stream>>>(srcp, dstp, bcur, btmp, e, nbk);
    k_bsort<<<nbk, 256, 0, stream>>>(btmp, boffs, csr, offs, dinv, n, e);
    k_embed<<<(n * HID + 255) / 256, 256, 0, stream>>>(x, We, be, h, n);

    const float* Wl[3]  = {W1, W2, W3};
    const float* bl[3]  = {b1, b2, b3};
    const float* gl[3]  = {g1, g2, g3};
    const float* btl[3] = {bt1, bt2, bt3};
    for (int L = 0; L < 3; ++L) {
        k_gemm128<<<(n + 63) / 64, 256, 0, stream>>>(h, Wl[L], dinv, th, n);
        hipMemsetAsync(bnS, 0, HID * 4, stream);
        hipMemsetAsync(bnSS, 0, HID * 4, stream);
        k_agg<<<1024, 256, 0, stream>>>(th, offs, csr, dinv, bl[L], agg, bnS, bnSS, n);
        k_bn_finalize<<<1, 128, 0, stream>>>(bnS, bnSS, gl[L], btl[L], bnA, bnC, n, 128);
        k_bn_apply_res<<<(n * HID + 255) / 256, 256, 0, stream>>>(agg, bnA, bnC, h, n * HID);
    }

    k_gemmf<<<(n + 63) / 64, 256, 0, stream>>>(h, Wf1, bf1, tf, n);
    hipMemsetAsync(bnS, 0, 32 * 4, stream);
    hipMemsetAsync(bnSS, 0, 32 * 4, stream);
    k_bn_stats32<<<512, 128, 0, stream>>>(tf, bnS, bnSS, n);
    k_bn_finalize<<<1, 32, 0, stream>>>(bnS, bnSS, gf, btf, bnA, bnC, n, 32);
    k_final<<<(n + 255) / 256, 256, 0, stream>>>(tf, bnA, bnC, Wf2, bf2, out, n);
}